// Round 11
// baseline (141.362 us; speedup 1.0000x reference)
//
#include <hip/hip_runtime.h>
#include <hip/hip_bf16.h>
#include <cstdint>
#include <cstddef>

#define T_TOTAL 32768
#define F_IN    73
#define H_FNN   512
#define D_FNN   256
#define H_RNN   128
#define G4      512
#define SEG     16
#define BURN    32
#define STEPS   (SEG + BURN)      // 48
#define NBLK    256              // 8 chains/block * 16 steps * 256 = 32768
#define CHUNK   4
#define XPAD    530              // chain stride = 2*XPAD dwords = 4 mod 32 -> 8 chains on 8 bank-groups
#define OUT_COLS 384
#define KP1     96

typedef short bf16x8 __attribute__((ext_vector_type(8)));
typedef float f32x4  __attribute__((ext_vector_type(4)));

// ---------------- helpers ----------------

__device__ __forceinline__ float fast_sigmoid(float x) {
    float e = __expf(-x);
    return __builtin_amdgcn_rcpf(1.f + e);
}
__device__ __forceinline__ float fast_tanh(float x) {
    float e = __expf(2.f * x);
    return 1.f - 2.f * __builtin_amdgcn_rcpf(e + 1.f);
}

// ---------------- one fused prep kernel (all bf16 operand staging) ----------------

#define N_A   (T_TOTAL * KP1)
#define N_W1  (H_FNN * KP1)
#define N_W2  (D_FNN * H_FNN)
#define N_WHH (G4 * H_RNN)
#define N_WIH (G4 * 32)
#define N_XD  (T_TOTAL * 32)
#define N_TOT (N_A + N_W1 + N_W2 + N_WHH + N_WIH + N_XD)

__global__ void prep_kernel(
    const float* __restrict__ features, const float* __restrict__ W1,
    const float* __restrict__ W2,       const float* __restrict__ W_ih,
    const float* __restrict__ b_ih,     const float* __restrict__ b_hh,
    const float* __restrict__ W_hh,
    __hip_bfloat16* __restrict__ Abf,   __hip_bfloat16* __restrict__ W1b,
    __hip_bfloat16* __restrict__ W2b,   __hip_bfloat16* __restrict__ Whh3,
    __hip_bfloat16* __restrict__ W_ihp, __hip_bfloat16* __restrict__ Xd)
{
    int idx = blockIdx.x * 256 + threadIdx.x;
    if (idx >= N_TOT) return;
    if (idx < N_A) {
        int r = idx / KP1, c = idx % KP1;
        Abf[idx] = __float2bfloat16(c < F_IN ? features[(size_t)r * F_IN + c] : 0.f);
    } else if ((idx -= N_A) < N_W1) {
        int n = idx / KP1, k = idx % KP1;
        W1b[idx] = __float2bfloat16(k < F_IN ? W1[(size_t)n * F_IN + k] : 0.f);
    } else if ((idx -= N_W1) < N_W2) {
        W2b[idx] = __float2bfloat16(W2[idx]);
    } else if ((idx -= N_W2) < N_WHH) {
        int np = idx >> 7, kp = idx & 127;
        int mfk = kp & 1, P = kp >> 1;
        int uk = (P >> 2) * 8 + mfk * 4 + (P & 3);
        int m = np >> 2, g = np & 3;
        Whh3[idx] = __float2bfloat16(W_hh[(size_t)(g * H_RNN + m) * H_RNN + uk]);
    } else if ((idx -= N_WHH) < N_WIH) {
        int n2 = idx >> 5, k = idx & 31;
        int P = n2 >> 3, mfv = (n2 >> 2) & 1, g = n2 & 3;
        int u = (P >> 2) * 8 + mfv * 4 + (P & 3);
        int j = g * H_RNN + u;
        float v = 0.f;
        if (k < 25)       v = W_ih[j * 25 + k];
        else if (k == 25) v = b_ih[j] + b_hh[j];
        W_ihp[idx] = __float2bfloat16(v);
    } else {
        idx -= N_WIH;
        int t = idx >> 5, k = idx & 31;
        float v = 0.f;
        if (k < 25)       v = features[(size_t)t * F_IN + (k == 0 ? 0 : 48 + k)];
        else if (k == 25) v = 1.f;
        Xd[idx] = __float2bfloat16(v);
    }
}

// ---------------- xgates via MFMA (transposed-D, bias folded) ----------------

__global__ __launch_bounds__(512, 2) void xgates_mfma(
    const __hip_bfloat16* __restrict__ Xd,     // [T][32]
    const __hip_bfloat16* __restrict__ W_ihp,  // [512][32] rows n''
    __hip_bfloat16* __restrict__ xg2)          // [T][512] cols n''
{
    const int tid = threadIdx.x;
    const int w8  = tid >> 6;
    const int l   = tid & 63;
    const int lr  = l & 15;
    const int lg  = l >> 4;
    const int t0  = blockIdx.x * 64;

    bf16x8 a[4];
#pragma unroll
    for (int mfx = 0; mfx < 4; ++mfx)
        a[mfx] = *reinterpret_cast<const bf16x8*>(
            W_ihp + (size_t)(w8 * 64 + mfx * 16 + lr) * 32 + lg * 8);

#pragma unroll
    for (int tt = 0; tt < 4; ++tt) {
        const int t = t0 + tt * 16 + lr;
        bf16x8 b = *reinterpret_cast<const bf16x8*>(Xd + (size_t)t * 32 + lg * 8);
#pragma unroll
        for (int mfx = 0; mfx < 4; ++mfx) {
            f32x4 acc = (f32x4){0.f, 0.f, 0.f, 0.f};
            acc = __builtin_amdgcn_mfma_f32_16x16x32_bf16(a[mfx], b, acc, 0, 0, 0);
            __hip_bfloat16 tmp[4];
#pragma unroll
            for (int r = 0; r < 4; ++r) tmp[r] = __float2bfloat16(acc[r]);
            *reinterpret_cast<uint2*>(xg2 + (size_t)t * G4 + w8 * 64 + mfx * 16 + lg * 4) =
                *reinterpret_cast<const uint2*>(tmp);
        }
    }
}

// ---------------- FNN via bf16 MFMA (unchanged, validated round 4) ----------------

__global__ __launch_bounds__(512, 2) void fnn_mfma(
    const __hip_bfloat16* __restrict__ Abf,
    const __hip_bfloat16* __restrict__ W1bf,
    const float* __restrict__ b1,
    const __hip_bfloat16* __restrict__ W2bf,
    const float* __restrict__ b2,
    float* __restrict__ out)
{
    __shared__ __attribute__((aligned(16))) __hip_bfloat16 c1[64][520];
    const int tid  = threadIdx.x;
    const int wid  = tid >> 6;
    const int lane = tid & 63;
    const int lr   = lane & 15;
    const int lg   = lane >> 4;
    const int wm   = wid >> 2;
    const int wn   = wid & 3;
    const int m0   = blockIdx.x * 64;

    f32x4 acc1[2][8];
#pragma unroll
    for (int i = 0; i < 2; ++i)
#pragma unroll
        for (int j = 0; j < 8; ++j)
            acc1[i][j] = (f32x4){0.f, 0.f, 0.f, 0.f};

#pragma unroll
    for (int ks = 0; ks < 3; ++ks) {
        const int k0 = ks * 32 + lg * 8;
        bf16x8 a[2], b[8];
#pragma unroll
        for (int mf = 0; mf < 2; ++mf) {
            const int row = m0 + wm * 32 + mf * 16 + lr;
            a[mf] = *reinterpret_cast<const bf16x8*>(Abf + (size_t)row * KP1 + k0);
        }
#pragma unroll
        for (int nf = 0; nf < 8; ++nf) {
            const int col = wn * 128 + nf * 16 + lr;
            b[nf] = *reinterpret_cast<const bf16x8*>(W1bf + (size_t)col * KP1 + k0);
        }
#pragma unroll
        for (int mf = 0; mf < 2; ++mf)
#pragma unroll
            for (int nf = 0; nf < 8; ++nf)
                acc1[mf][nf] = __builtin_amdgcn_mfma_f32_16x16x32_bf16(
                    a[mf], b[nf], acc1[mf][nf], 0, 0, 0);
    }

#pragma unroll
    for (int nf = 0; nf < 8; ++nf) {
        const int col = wn * 128 + nf * 16 + lr;
        const float bv = b1[col];
#pragma unroll
        for (int mf = 0; mf < 2; ++mf) {
            const int rowb = wm * 32 + mf * 16 + lg * 4;
#pragma unroll
            for (int r = 0; r < 4; ++r) {
                float v = fmaxf(acc1[mf][nf][r] + bv, 0.f);
                c1[rowb + r][col] = __float2bfloat16(v);
            }
        }
    }
    __syncthreads();

    f32x4 acc2[2][4];
#pragma unroll
    for (int i = 0; i < 2; ++i)
#pragma unroll
        for (int j = 0; j < 4; ++j)
            acc2[i][j] = (f32x4){0.f, 0.f, 0.f, 0.f};

#pragma unroll
    for (int ks = 0; ks < 16; ++ks) {
        const int k0 = ks * 32 + lg * 8;
        bf16x8 a[2], b[4];
#pragma unroll
        for (int mf = 0; mf < 2; ++mf) {
            const int row = wm * 32 + mf * 16 + lr;
            a[mf] = *reinterpret_cast<const bf16x8*>(&c1[row][k0]);
        }
#pragma unroll
        for (int nf = 0; nf < 4; ++nf) {
            const int col = wn * 64 + nf * 16 + lr;
            b[nf] = *reinterpret_cast<const bf16x8*>(W2bf + (size_t)col * H_FNN + k0);
        }
#pragma unroll
        for (int mf = 0; mf < 2; ++mf)
#pragma unroll
            for (int nf = 0; nf < 4; ++nf)
                acc2[mf][nf] = __builtin_amdgcn_mfma_f32_16x16x32_bf16(
                    a[mf], b[nf], acc2[mf][nf], 0, 0, 0);
    }

#pragma unroll
    for (int nf = 0; nf < 4; ++nf) {
        const int col = wn * 64 + nf * 16 + lr;
        const float bv = b2[col];
#pragma unroll
        for (int mf = 0; mf < 2; ++mf) {
#pragma unroll
            for (int r = 0; r < 4; ++r) {
                const int row = m0 + wm * 32 + mf * 16 + lg * 4 + r;
                float v = fmaxf(acc2[mf][nf][r] + bv, 0.f);
                out[(size_t)row * OUT_COLS + col] = v;
                out[((size_t)T_TOTAL + row) * OUT_COLS + col] = v;
            }
        }
    }
}

// ---------------- swapped-operand MFMA LSTM, pinned weights ----------------
// Round-10 forensics: VGPR=52 + FETCH 25.7MB = the loop-invariant afr A-frags
// were re-loaded from GLOBAL every step (8 dwordx4 + vmcnt on the critical
// path). Pinning is SAFE here (unlike rounds 2-5) because afr feeds MFMA,
// which reads A-operands from VGPR or AGPR natively -- no per-use move cost.
// Budget: waves_per_eu(4,4) -> 128 VGPR/wave; 52+32 pinned ~ 84. Fits.

__global__ __attribute__((amdgpu_flat_work_group_size(1024, 1024),
                          amdgpu_waves_per_eu(4, 4)))
void lstm_mfma6(
    const __hip_bfloat16* __restrict__ xg2,    // [T][512] cols n''
    const __hip_bfloat16* __restrict__ Whh3,   // [512][128] rows n', cols k'
    float* __restrict__ out)
{
    const int tid = threadIdx.x;
    const int l   = tid & 63;
    const int w   = tid >> 6;          // wave 0..15
    const int lr  = l & 15;
    const int lg  = l >> 4;
    const int ch  = l & 7;             // this lane's chain
    const int mfu = (l >> 3) & 1;      // which mf-half this lane updates
    const int u_up = w * 8 + mfu * 4 + lg;   // this lane's hidden unit
    const int P_up = w * 4 + lg;             // k'-pair index

    __shared__ __attribute__((aligned(16))) __hip_bfloat16 hB[2][8][144];          // 4.6 KiB
    __shared__ __attribute__((aligned(16))) __hip_bfloat16 xstage[2][8][CHUNK][XPAD]; // 68 KiB
    __shared__ __attribute__((aligned(16))) __hip_bfloat16 outbuf[8][17][132];     // 36 KiB

    // A-fragments (static): Whh3 rows w*32+mf*16+lr — PINNED in registers
    bf16x8 afr[2][4];
#pragma unroll
    for (int mf = 0; mf < 2; ++mf)
#pragma unroll
        for (int ks = 0; ks < 4; ++ks)
            afr[mf][ks] = *reinterpret_cast<const bf16x8*>(
                Whh3 + (size_t)(w * 32 + mf * 16 + lr) * H_RNN + ks * 32 + lg * 8);
#pragma unroll
    for (int mf = 0; mf < 2; ++mf)
#pragma unroll
        for (int ks = 0; ks < 4; ++ks)
            asm volatile("" : "+v"(afr[mf][ks]));   // non-rematerializable -> stays resident

    const int tbase = blockIdx.x * 128 - BURN;

    auto stage_load = [&](int chunk, uint4 (&tmp)[2]) {
#pragma unroll
        for (int k = 0; k < 2; ++k) {
            int idx = tid + k * 1024;
            int row = idx >> 6;                 // 0..31 = chain*4 + step
            int col = (idx & 63) * 8;
            int t = tbase + (row >> 2) * SEG + chunk * CHUNK + (row & 3);
            t = t < 0 ? 0 : t;
            tmp[k] = *reinterpret_cast<const uint4*>(xg2 + (size_t)t * G4 + col);
        }
    };
    auto stage_write = [&](int chunk, const uint4 (&tmp)[2]) {
        const int buf = chunk & 1;
#pragma unroll
        for (int k = 0; k < 2; ++k) {
            int idx = tid + k * 1024;
            int row = idx >> 6;
            int col = (idx & 63) * 8;
            *reinterpret_cast<uint4*>(&xstage[buf][row >> 2][row & 3][col]) = tmp[k];
        }
    };

    // prologue: zero hB (both buffers), stage chunk 0
    {
        uint32_t* hz = (uint32_t*)hB;            // 1152 dwords
        if (tid < 1152) hz[tid] = 0u;
        if (tid + 1024 < 1152) hz[tid + 1024] = 0u;
        uint4 tmp[2];
        stage_load(0, tmp);
        stage_write(0, tmp);
    }
    __syncthreads();

    const int tb_c = tbase + ch * SEG;
    float c_st = 0.f;
    int p = 0;

    for (int i = 0; i < STEPS; ++i) {
        const bool do_stage = ((i & (CHUNK - 1)) == CHUNK - 1) && (i + 1 < STEPS);
        uint4 tmp[2];
        if (do_stage) stage_load((i + 1) >> 2, tmp);

        // B-fragments: H^T, col = chain (lanes lr>=8 duplicate rows -> valid dups)
        bf16x8 bfrg[4];
#pragma unroll
        for (int ks = 0; ks < 4; ++ks)
            bfrg[ks] = *reinterpret_cast<const bf16x8*>(&hB[p][lr & 7][ks * 32 + lg * 8]);

        f32x4 acc0 = (f32x4){0.f, 0.f, 0.f, 0.f};
        f32x4 acc1 = (f32x4){0.f, 0.f, 0.f, 0.f};
#pragma unroll
        for (int ks = 0; ks < 4; ++ks) {
            acc0 = __builtin_amdgcn_mfma_f32_16x16x32_bf16(afr[0][ks], bfrg[ks], acc0, 0, 0, 0);
            acc1 = __builtin_amdgcn_mfma_f32_16x16x32_bf16(afr[1][ks], bfrg[ks], acc1, 0, 0, 0);
        }

        // x-gates: one b64, cols n'' = 8*P_up + 4*mfu + {0..3} = gates i,f,g,o
        uint2 xr = *reinterpret_cast<const uint2*>(
            &xstage[(i >> 2) & 1][ch][i & (CHUNK - 1)][8 * P_up + 4 * mfu]);

        float g0 = (mfu ? acc1[0] : acc0[0]) + __uint_as_float(xr.x << 16);
        float g1 = (mfu ? acc1[1] : acc0[1]) + __uint_as_float(xr.x & 0xffff0000u);
        float g2 = (mfu ? acc1[2] : acc0[2]) + __uint_as_float(xr.y << 16);
        float g3 = (mfu ? acc1[3] : acc0[3]) + __uint_as_float(xr.y & 0xffff0000u);

        float I = fast_sigmoid(g0);
        float F = fast_sigmoid(g1);
        float G = fast_tanh  (g2);
        float O = fast_sigmoid(g3);
        float cn = F * c_st + I * G;
        const bool neg = (tb_c + i) < 0;
        c_st = neg ? 0.f : cn;
        float h = neg ? 0.f : O * fast_tanh(c_st);

        // h -> next B buffer (k' = 2*P_up + mfu), one b16 per lane
        hB[p ^ 1][ch][2 * P_up + mfu] = __float2bfloat16(h);

        if (i >= BURN)
            outbuf[ch][i - BURN][u_up] = __float2bfloat16(fmaxf(h, 0.f));

        if (do_stage) stage_write((i + 1) >> 2, tmp);

        __syncthreads();
        p ^= 1;
    }

    // tail: stream outputs coalesced (dword = 2 bf16)
#pragma unroll
    for (int k = 0; k < 8; ++k) {
        int idx = k * 1024 + tid;                 // 0..8191 dwords
        int s  = idx >> 10;
        int st = (idx >> 6) & 15;
        int md = idx & 63;
        uint32_t v2 = *reinterpret_cast<const uint32_t*>(&outbuf[s][st][md * 2]);
        float v0 = __uint_as_float(v2 << 16);
        float v1 = __uint_as_float(v2 & 0xffff0000u);
        size_t t = (size_t)(blockIdx.x * 8 + s) * SEG + st;
        float* po = out + t * OUT_COLS + 256 + md * 2;
        po[0] = v0; po[1] = v1;
        po += (size_t)T_TOTAL * OUT_COLS;
        po[0] = v0; po[1] = v1;
    }
}

// ---------------- host ----------------

extern "C" void kernel_launch(void* const* d_in, const int* in_sizes, int n_in,
                              void* d_out, int out_size, void* d_ws, size_t ws_size,
                              hipStream_t stream) {
    const float* features = (const float*)d_in[0];
    const float* W1   = (const float*)d_in[1];
    const float* b1   = (const float*)d_in[2];
    const float* W2   = (const float*)d_in[3];
    const float* b2   = (const float*)d_in[4];
    const float* W_ih = (const float*)d_in[5];
    const float* b_ih = (const float*)d_in[6];
    const float* W_hh = (const float*)d_in[7];
    const float* b_hh = (const float*)d_in[8];
    float* out = (float*)d_out;

    char* ws = (char*)d_ws;
    __hip_bfloat16* xg2   = (__hip_bfloat16*)ws;                     // 32 MiB
    size_t off = (size_t)T_TOTAL * G4 * 2;
    __hip_bfloat16* Abf   = (__hip_bfloat16*)(ws + off); off += (size_t)N_A * 2;
    __hip_bfloat16* W1b   = (__hip_bfloat16*)(ws + off); off += (size_t)N_W1 * 2;
    __hip_bfloat16* W2b   = (__hip_bfloat16*)(ws + off); off += (size_t)N_W2 * 2;
    __hip_bfloat16* Whh3  = (__hip_bfloat16*)(ws + off); off += (size_t)N_WHH * 2;
    __hip_bfloat16* W_ihp = (__hip_bfloat16*)(ws + off); off += (size_t)N_WIH * 2;
    __hip_bfloat16* Xd    = (__hip_bfloat16*)(ws + off);

    hipLaunchKernelGGL(prep_kernel, dim3((N_TOT + 255) / 256), dim3(256), 0, stream,
                       features, W1, W2, W_ih, b_ih, b_hh, W_hh,
                       Abf, W1b, W2b, Whh3, W_ihp, Xd);
    hipLaunchKernelGGL(xgates_mfma, dim3(T_TOTAL / 64), dim3(512), 0, stream,
                       Xd, W_ihp, xg2);
    hipLaunchKernelGGL(fnn_mfma,    dim3(T_TOTAL / 64), dim3(512), 0, stream,
                       Abf, W1b, b1, W2b, b2, out);
    hipLaunchKernelGGL(lstm_mfma6,  dim3(NBLK), dim3(1024), 0, stream, xg2, Whh3, out);
}

// Round 12
// 134.698 us; speedup vs baseline: 1.0495x; 1.0495x over previous
//
#include <hip/hip_runtime.h>
#include <hip/hip_bf16.h>
#include <cstdint>
#include <cstddef>

#define T_TOTAL 32768
#define F_IN    73
#define H_FNN   512
#define D_FNN   256
#define H_RNN   128
#define G4      512
#define SEG     16
#define BURN    32
#define STEPS   (SEG + BURN)      // 48
#define NBLK    256              // 8 chains/block * 16 steps * 256 = 32768
#define CHUNK   4
#define XPAD    524              // reverted: 530 doubled bank conflicts (R11)
#define OUT_COLS 384
#define KP1     96

typedef short bf16x8 __attribute__((ext_vector_type(8)));
typedef float f32x4  __attribute__((ext_vector_type(4)));

// ---------------- helpers ----------------

__device__ __forceinline__ float fast_sigmoid(float x) {
    float e = __expf(-x);
    return __builtin_amdgcn_rcpf(1.f + e);
}
__device__ __forceinline__ float fast_tanh(float x) {
    float e = __expf(2.f * x);
    return 1.f - 2.f * __builtin_amdgcn_rcpf(e + 1.f);
}

// ---------------- one fused prep kernel (all bf16 operand staging) ----------------

#define N_A   (T_TOTAL * KP1)
#define N_W1  (H_FNN * KP1)
#define N_W2  (D_FNN * H_FNN)
#define N_WHH (G4 * H_RNN)
#define N_WIH (G4 * 32)
#define N_XD  (T_TOTAL * 32)
#define N_TOT (N_A + N_W1 + N_W2 + N_WHH + N_WIH + N_XD)

__global__ void prep_kernel(
    const float* __restrict__ features, const float* __restrict__ W1,
    const float* __restrict__ W2,       const float* __restrict__ W_ih,
    const float* __restrict__ b_ih,     const float* __restrict__ b_hh,
    const float* __restrict__ W_hh,
    __hip_bfloat16* __restrict__ Abf,   __hip_bfloat16* __restrict__ W1b,
    __hip_bfloat16* __restrict__ W2b,   __hip_bfloat16* __restrict__ Whh3,
    __hip_bfloat16* __restrict__ W_ihp, __hip_bfloat16* __restrict__ Xd)
{
    int idx = blockIdx.x * 256 + threadIdx.x;
    if (idx >= N_TOT) return;
    if (idx < N_A) {
        int r = idx / KP1, c = idx % KP1;
        Abf[idx] = __float2bfloat16(c < F_IN ? features[(size_t)r * F_IN + c] : 0.f);
    } else if ((idx -= N_A) < N_W1) {
        int n = idx / KP1, k = idx % KP1;
        W1b[idx] = __float2bfloat16(k < F_IN ? W1[(size_t)n * F_IN + k] : 0.f);
    } else if ((idx -= N_W1) < N_W2) {
        W2b[idx] = __float2bfloat16(W2[idx]);
    } else if ((idx -= N_W2) < N_WHH) {
        int np = idx >> 7, kp = idx & 127;
        int mfk = kp & 1, P = kp >> 1;
        int uk = (P >> 2) * 8 + mfk * 4 + (P & 3);
        int m = np >> 2, g = np & 3;
        Whh3[idx] = __float2bfloat16(W_hh[(size_t)(g * H_RNN + m) * H_RNN + uk]);
    } else if ((idx -= N_WHH) < N_WIH) {
        int n2 = idx >> 5, k = idx & 31;
        int P = n2 >> 3, mfv = (n2 >> 2) & 1, g = n2 & 3;
        int u = (P >> 2) * 8 + mfv * 4 + (P & 3);
        int j = g * H_RNN + u;
        float v = 0.f;
        if (k < 25)       v = W_ih[j * 25 + k];
        else if (k == 25) v = b_ih[j] + b_hh[j];
        W_ihp[idx] = __float2bfloat16(v);
    } else {
        idx -= N_WIH;
        int t = idx >> 5, k = idx & 31;
        float v = 0.f;
        if (k < 25)       v = features[(size_t)t * F_IN + (k == 0 ? 0 : 48 + k)];
        else if (k == 25) v = 1.f;
        Xd[idx] = __float2bfloat16(v);
    }
}

// ---------------- xgates via MFMA (transposed-D, bias folded) ----------------

__global__ __launch_bounds__(512, 2) void xgates_mfma(
    const __hip_bfloat16* __restrict__ Xd,     // [T][32]
    const __hip_bfloat16* __restrict__ W_ihp,  // [512][32] rows n''
    __hip_bfloat16* __restrict__ xg2)          // [T][512] cols n''
{
    const int tid = threadIdx.x;
    const int w8  = tid >> 6;
    const int l   = tid & 63;
    const int lr  = l & 15;
    const int lg  = l >> 4;
    const int t0  = blockIdx.x * 64;

    bf16x8 a[4];
#pragma unroll
    for (int mfx = 0; mfx < 4; ++mfx)
        a[mfx] = *reinterpret_cast<const bf16x8*>(
            W_ihp + (size_t)(w8 * 64 + mfx * 16 + lr) * 32 + lg * 8);

#pragma unroll
    for (int tt = 0; tt < 4; ++tt) {
        const int t = t0 + tt * 16 + lr;
        bf16x8 b = *reinterpret_cast<const bf16x8*>(Xd + (size_t)t * 32 + lg * 8);
#pragma unroll
        for (int mfx = 0; mfx < 4; ++mfx) {
            f32x4 acc = (f32x4){0.f, 0.f, 0.f, 0.f};
            acc = __builtin_amdgcn_mfma_f32_16x16x32_bf16(a[mfx], b, acc, 0, 0, 0);
            __hip_bfloat16 tmp[4];
#pragma unroll
            for (int r = 0; r < 4; ++r) tmp[r] = __float2bfloat16(acc[r]);
            *reinterpret_cast<uint2*>(xg2 + (size_t)t * G4 + w8 * 64 + mfx * 16 + lg * 4) =
                *reinterpret_cast<const uint2*>(tmp);
        }
    }
}

// ---------------- FNN via bf16 MFMA (unchanged, validated round 4) ----------------

__global__ __launch_bounds__(512, 2) void fnn_mfma(
    const __hip_bfloat16* __restrict__ Abf,
    const __hip_bfloat16* __restrict__ W1bf,
    const float* __restrict__ b1,
    const __hip_bfloat16* __restrict__ W2bf,
    const float* __restrict__ b2,
    float* __restrict__ out)
{
    __shared__ __attribute__((aligned(16))) __hip_bfloat16 c1[64][520];
    const int tid  = threadIdx.x;
    const int wid  = tid >> 6;
    const int lane = tid & 63;
    const int lr   = lane & 15;
    const int lg   = lane >> 4;
    const int wm   = wid >> 2;
    const int wn   = wid & 3;
    const int m0   = blockIdx.x * 64;

    f32x4 acc1[2][8];
#pragma unroll
    for (int i = 0; i < 2; ++i)
#pragma unroll
        for (int j = 0; j < 8; ++j)
            acc1[i][j] = (f32x4){0.f, 0.f, 0.f, 0.f};

#pragma unroll
    for (int ks = 0; ks < 3; ++ks) {
        const int k0 = ks * 32 + lg * 8;
        bf16x8 a[2], b[8];
#pragma unroll
        for (int mf = 0; mf < 2; ++mf) {
            const int row = m0 + wm * 32 + mf * 16 + lr;
            a[mf] = *reinterpret_cast<const bf16x8*>(Abf + (size_t)row * KP1 + k0);
        }
#pragma unroll
        for (int nf = 0; nf < 8; ++nf) {
            const int col = wn * 128 + nf * 16 + lr;
            b[nf] = *reinterpret_cast<const bf16x8*>(W1bf + (size_t)col * KP1 + k0);
        }
#pragma unroll
        for (int mf = 0; mf < 2; ++mf)
#pragma unroll
            for (int nf = 0; nf < 8; ++nf)
                acc1[mf][nf] = __builtin_amdgcn_mfma_f32_16x16x32_bf16(
                    a[mf], b[nf], acc1[mf][nf], 0, 0, 0);
    }

#pragma unroll
    for (int nf = 0; nf < 8; ++nf) {
        const int col = wn * 128 + nf * 16 + lr;
        const float bv = b1[col];
#pragma unroll
        for (int mf = 0; mf < 2; ++mf) {
            const int rowb = wm * 32 + mf * 16 + lg * 4;
#pragma unroll
            for (int r = 0; r < 4; ++r) {
                float v = fmaxf(acc1[mf][nf][r] + bv, 0.f);
                c1[rowb + r][col] = __float2bfloat16(v);
            }
        }
    }
    __syncthreads();

    f32x4 acc2[2][4];
#pragma unroll
    for (int i = 0; i < 2; ++i)
#pragma unroll
        for (int j = 0; j < 4; ++j)
            acc2[i][j] = (f32x4){0.f, 0.f, 0.f, 0.f};

#pragma unroll
    for (int ks = 0; ks < 16; ++ks) {
        const int k0 = ks * 32 + lg * 8;
        bf16x8 a[2], b[4];
#pragma unroll
        for (int mf = 0; mf < 2; ++mf) {
            const int row = wm * 32 + mf * 16 + lr;
            a[mf] = *reinterpret_cast<const bf16x8*>(&c1[row][k0]);
        }
#pragma unroll
        for (int nf = 0; nf < 4; ++nf) {
            const int col = wn * 64 + nf * 16 + lr;
            b[nf] = *reinterpret_cast<const bf16x8*>(W2bf + (size_t)col * H_FNN + k0);
        }
#pragma unroll
        for (int mf = 0; mf < 2; ++mf)
#pragma unroll
            for (int nf = 0; nf < 4; ++nf)
                acc2[mf][nf] = __builtin_amdgcn_mfma_f32_16x16x32_bf16(
                    a[mf], b[nf], acc2[mf][nf], 0, 0, 0);
    }

#pragma unroll
    for (int nf = 0; nf < 4; ++nf) {
        const int col = wn * 64 + nf * 16 + lr;
        const float bv = b2[col];
#pragma unroll
        for (int mf = 0; mf < 2; ++mf) {
#pragma unroll
            for (int r = 0; r < 4; ++r) {
                const int row = m0 + wm * 32 + mf * 16 + lg * 4 + r;
                float v = fmaxf(acc2[mf][nf][r] + bv, 0.f);
                out[(size_t)row * OUT_COLS + col] = v;
                out[((size_t)T_TOTAL + row) * OUT_COLS + col] = v;
            }
        }
    }
}

// ---------------- swapped-operand MFMA LSTM, AGPR-pinned weights ----------------
// R11 lesson: asm("+v") pins are point-in-time; the RA still remats the 32
// loop-invariant weight VGPRs from L2 every step (FETCH 27MB, ~300cy vmcnt on
// the chain). This round: pin into ACCUMULATOR registers with asm("+a").
// (a) MFMA reads A-operands from AGPRs natively -> zero per-use cost;
// (b) LLVM cannot remat a global load INTO an AGPR (needs VGPR intermediate
//     + accvgpr_write, defeating the heuristic) and AGPR spills are heavily
//     penalized -> values should finally stay resident.
// Unified-RF budget: 52 arch + 32 acc = 84 <= 128 @ 4 waves/SIMD. Fits.

__global__ __attribute__((amdgpu_flat_work_group_size(1024, 1024),
                          amdgpu_waves_per_eu(4, 4)))
void lstm_mfma7(
    const __hip_bfloat16* __restrict__ xg2,    // [T][512] cols n''
    const __hip_bfloat16* __restrict__ Whh3,   // [512][128] rows n', cols k'
    float* __restrict__ out)
{
    const int tid = threadIdx.x;
    const int l   = tid & 63;
    const int w   = tid >> 6;          // wave 0..15
    const int lr  = l & 15;
    const int lg  = l >> 4;
    const int ch  = l & 7;             // this lane's chain
    const int mfu = (l >> 3) & 1;      // which mf-half this lane updates
    const int u_up = w * 8 + mfu * 4 + lg;   // this lane's hidden unit
    const int P_up = w * 4 + lg;             // k'-pair index

    __shared__ __attribute__((aligned(16))) __hip_bfloat16 hB[2][8][144];          // 4.6 KiB
    __shared__ __attribute__((aligned(16))) __hip_bfloat16 xstage[2][8][CHUNK][XPAD]; // 67 KiB
    __shared__ __attribute__((aligned(16))) __hip_bfloat16 outbuf[8][17][132];     // 36 KiB

    // A-fragments (loop-invariant): Whh3 rows w*32+mf*16+lr — pinned in AGPRs
    bf16x8 afr[2][4];
#pragma unroll
    for (int mf = 0; mf < 2; ++mf)
#pragma unroll
        for (int ks = 0; ks < 4; ++ks)
            afr[mf][ks] = *reinterpret_cast<const bf16x8*>(
                Whh3 + (size_t)(w * 32 + mf * 16 + lr) * H_RNN + ks * 32 + lg * 8);
#pragma unroll
    for (int mf = 0; mf < 2; ++mf)
#pragma unroll
        for (int ks = 0; ks < 4; ++ks)
            asm volatile("" : "+a"(afr[mf][ks]));   // force AGPR residency

    const int tbase = blockIdx.x * 128 - BURN;

    auto stage_load = [&](int chunk, uint4 (&tmp)[2]) {
#pragma unroll
        for (int k = 0; k < 2; ++k) {
            int idx = tid + k * 1024;
            int row = idx >> 6;                 // 0..31 = chain*4 + step
            int col = (idx & 63) * 8;
            int t = tbase + (row >> 2) * SEG + chunk * CHUNK + (row & 3);
            t = t < 0 ? 0 : t;
            tmp[k] = *reinterpret_cast<const uint4*>(xg2 + (size_t)t * G4 + col);
        }
    };
    auto stage_write = [&](int chunk, const uint4 (&tmp)[2]) {
        const int buf = chunk & 1;
#pragma unroll
        for (int k = 0; k < 2; ++k) {
            int idx = tid + k * 1024;
            int row = idx >> 6;
            int col = (idx & 63) * 8;
            *reinterpret_cast<uint4*>(&xstage[buf][row >> 2][row & 3][col]) = tmp[k];
        }
    };

    // prologue: zero hB (both buffers), stage chunk 0
    {
        uint32_t* hz = (uint32_t*)hB;            // 1152 dwords
        if (tid < 1152) hz[tid] = 0u;
        if (tid + 1024 < 1152) hz[tid + 1024] = 0u;
        uint4 tmp[2];
        stage_load(0, tmp);
        stage_write(0, tmp);
    }
    __syncthreads();

    const int tb_c = tbase + ch * SEG;
    float c_st = 0.f;
    int p = 0;

    for (int i = 0; i < STEPS; ++i) {
        const bool do_stage = ((i & (CHUNK - 1)) == CHUNK - 1) && (i + 1 < STEPS);
        uint4 tmp[2];
        if (do_stage) stage_load((i + 1) >> 2, tmp);

        // B-fragments: H^T, col = chain (lanes lr>=8 duplicate rows -> valid dups)
        bf16x8 bfrg[4];
#pragma unroll
        for (int ks = 0; ks < 4; ++ks)
            bfrg[ks] = *reinterpret_cast<const bf16x8*>(&hB[p][lr & 7][ks * 32 + lg * 8]);

        f32x4 acc0 = (f32x4){0.f, 0.f, 0.f, 0.f};
        f32x4 acc1 = (f32x4){0.f, 0.f, 0.f, 0.f};
#pragma unroll
        for (int ks = 0; ks < 4; ++ks) {
            acc0 = __builtin_amdgcn_mfma_f32_16x16x32_bf16(afr[0][ks], bfrg[ks], acc0, 0, 0, 0);
            acc1 = __builtin_amdgcn_mfma_f32_16x16x32_bf16(afr[1][ks], bfrg[ks], acc1, 0, 0, 0);
        }

        // x-gates: one b64, cols n'' = 8*P_up + 4*mfu + {0..3} = gates i,f,g,o
        uint2 xr = *reinterpret_cast<const uint2*>(
            &xstage[(i >> 2) & 1][ch][i & (CHUNK - 1)][8 * P_up + 4 * mfu]);

        float g0 = (mfu ? acc1[0] : acc0[0]) + __uint_as_float(xr.x << 16);
        float g1 = (mfu ? acc1[1] : acc0[1]) + __uint_as_float(xr.x & 0xffff0000u);
        float g2 = (mfu ? acc1[2] : acc0[2]) + __uint_as_float(xr.y << 16);
        float g3 = (mfu ? acc1[3] : acc0[3]) + __uint_as_float(xr.y & 0xffff0000u);

        float I = fast_sigmoid(g0);
        float F = fast_sigmoid(g1);
        float G = fast_tanh  (g2);
        float O = fast_sigmoid(g3);
        float cn = F * c_st + I * G;
        const bool neg = (tb_c + i) < 0;
        c_st = neg ? 0.f : cn;
        float h = neg ? 0.f : O * fast_tanh(c_st);

        // h -> next B buffer (k' = 2*P_up + mfu), one b16 per lane
        hB[p ^ 1][ch][2 * P_up + mfu] = __float2bfloat16(h);

        if (i >= BURN)
            outbuf[ch][i - BURN][u_up] = __float2bfloat16(fmaxf(h, 0.f));

        if (do_stage) stage_write((i + 1) >> 2, tmp);

        __syncthreads();
        p ^= 1;
    }

    // tail: stream outputs coalesced (dword = 2 bf16)
#pragma unroll
    for (int k = 0; k < 8; ++k) {
        int idx = k * 1024 + tid;                 // 0..8191 dwords
        int s  = idx >> 10;
        int st = (idx >> 6) & 15;
        int md = idx & 63;
        uint32_t v2 = *reinterpret_cast<const uint32_t*>(&outbuf[s][st][md * 2]);
        float v0 = __uint_as_float(v2 << 16);
        float v1 = __uint_as_float(v2 & 0xffff0000u);
        size_t t = (size_t)(blockIdx.x * 8 + s) * SEG + st;
        float* po = out + t * OUT_COLS + 256 + md * 2;
        po[0] = v0; po[1] = v1;
        po += (size_t)T_TOTAL * OUT_COLS;
        po[0] = v0; po[1] = v1;
    }
}

// ---------------- host ----------------

extern "C" void kernel_launch(void* const* d_in, const int* in_sizes, int n_in,
                              void* d_out, int out_size, void* d_ws, size_t ws_size,
                              hipStream_t stream) {
    const float* features = (const float*)d_in[0];
    const float* W1   = (const float*)d_in[1];
    const float* b1   = (const float*)d_in[2];
    const float* W2   = (const float*)d_in[3];
    const float* b2   = (const float*)d_in[4];
    const float* W_ih = (const float*)d_in[5];
    const float* b_ih = (const float*)d_in[6];
    const float* W_hh = (const float*)d_in[7];
    const float* b_hh = (const float*)d_in[8];
    float* out = (float*)d_out;

    char* ws = (char*)d_ws;
    __hip_bfloat16* xg2   = (__hip_bfloat16*)ws;                     // 32 MiB
    size_t off = (size_t)T_TOTAL * G4 * 2;
    __hip_bfloat16* Abf   = (__hip_bfloat16*)(ws + off); off += (size_t)N_A * 2;
    __hip_bfloat16* W1b   = (__hip_bfloat16*)(ws + off); off += (size_t)N_W1 * 2;
    __hip_bfloat16* W2b   = (__hip_bfloat16*)(ws + off); off += (size_t)N_W2 * 2;
    __hip_bfloat16* Whh3  = (__hip_bfloat16*)(ws + off); off += (size_t)N_WHH * 2;
    __hip_bfloat16* W_ihp = (__hip_bfloat16*)(ws + off); off += (size_t)N_WIH * 2;
    __hip_bfloat16* Xd    = (__hip_bfloat16*)(ws + off);

    hipLaunchKernelGGL(prep_kernel, dim3((N_TOT + 255) / 256), dim3(256), 0, stream,
                       features, W1, W2, W_ih, b_ih, b_hh, W_hh,
                       Abf, W1b, W2b, Whh3, W_ihp, Xd);
    hipLaunchKernelGGL(xgates_mfma, dim3(T_TOTAL / 64), dim3(512), 0, stream,
                       Xd, W_ihp, xg2);
    hipLaunchKernelGGL(fnn_mfma,    dim3(T_TOTAL / 64), dim3(512), 0, stream,
                       Abf, W1b, b1, W2b, b2, out);
    hipLaunchKernelGGL(lstm_mfma7,  dim3(NBLK), dim3(1024), 0, stream, xg2, Whh3, out);
}

// Round 13
// 125.507 us; speedup vs baseline: 1.1263x; 1.0732x over previous
//
#include <hip/hip_runtime.h>
#include <hip/hip_bf16.h>
#include <cstdint>
#include <cstddef>

#define T_TOTAL 32768
#define F_IN    73
#define H_FNN   512
#define D_FNN   256
#define H_RNN   128
#define G4      512
#define SEG     16
#define BURN    32
#define STEPS   (SEG + BURN)      // 48
#define CPB     4                // chains per block
#define NBLK    512              // 512 blocks x 4 chains x 16 steps = 32768; 2 blocks/CU
#define OUT_COLS 384
#define KP1     96

typedef short bf16x8 __attribute__((ext_vector_type(8)));
typedef float f32x4  __attribute__((ext_vector_type(4)));

// ---------------- helpers ----------------

__device__ __forceinline__ float fast_sigmoid(float x) {
    float e = __expf(-x);
    return __builtin_amdgcn_rcpf(1.f + e);
}
__device__ __forceinline__ float fast_tanh(float x) {
    float e = __expf(2.f * x);
    return 1.f - 2.f * __builtin_amdgcn_rcpf(e + 1.f);
}

// ---------------- one fused prep kernel (all bf16 operand staging) ----------------
// Whh3[n'][k]: n' = w*64 + nf*16 + lg*4 + r  ->  gate r of unit u = w*16+nf*4+lg,
//              col k = source unit (identity).  W_ihp rows n'' = 4u+g (bias col 25).
// Xd[T][32]: D_SET gather, col 25 = 1.0 (bias trick).

#define N_A   (T_TOTAL * KP1)
#define N_W1  (H_FNN * KP1)
#define N_W2  (D_FNN * H_FNN)
#define N_WHH (G4 * H_RNN)
#define N_WIH (G4 * 32)
#define N_XD  (T_TOTAL * 32)
#define N_TOT (N_A + N_W1 + N_W2 + N_WHH + N_WIH + N_XD)

__global__ void prep_kernel(
    const float* __restrict__ features, const float* __restrict__ W1,
    const float* __restrict__ W2,       const float* __restrict__ W_ih,
    const float* __restrict__ b_ih,     const float* __restrict__ b_hh,
    const float* __restrict__ W_hh,
    __hip_bfloat16* __restrict__ Abf,   __hip_bfloat16* __restrict__ W1b,
    __hip_bfloat16* __restrict__ W2b,   __hip_bfloat16* __restrict__ Whh3,
    __hip_bfloat16* __restrict__ W_ihp, __hip_bfloat16* __restrict__ Xd)
{
    int idx = blockIdx.x * 256 + threadIdx.x;
    if (idx >= N_TOT) return;
    if (idx < N_A) {
        int r = idx / KP1, c = idx % KP1;
        Abf[idx] = __float2bfloat16(c < F_IN ? features[(size_t)r * F_IN + c] : 0.f);
    } else if ((idx -= N_A) < N_W1) {
        int n = idx / KP1, k = idx % KP1;
        W1b[idx] = __float2bfloat16(k < F_IN ? W1[(size_t)n * F_IN + k] : 0.f);
    } else if ((idx -= N_W1) < N_W2) {
        W2b[idx] = __float2bfloat16(W2[idx]);
    } else if ((idx -= N_W2) < N_WHH) {
        int np = idx >> 7, k = idx & 127;
        int w = np >> 6, nf = (np >> 4) & 3, l4 = (np >> 2) & 3, r = np & 3;
        int u = w * 16 + nf * 4 + l4;
        Whh3[idx] = __float2bfloat16(W_hh[(size_t)(r * H_RNN + u) * H_RNN + k]);
    } else if ((idx -= N_WHH) < N_WIH) {
        int n2 = idx >> 5, k = idx & 31;
        int u = n2 >> 2, g = n2 & 3;
        int j = g * H_RNN + u;
        float v = 0.f;
        if (k < 25)       v = W_ih[j * 25 + k];
        else if (k == 25) v = b_ih[j] + b_hh[j];
        W_ihp[idx] = __float2bfloat16(v);
    } else {
        idx -= N_WIH;
        int t = idx >> 5, k = idx & 31;
        float v = 0.f;
        if (k < 25)       v = features[(size_t)t * F_IN + (k == 0 ? 0 : 48 + k)];
        else if (k == 25) v = 1.f;
        Xd[idx] = __float2bfloat16(v);
    }
}

// ---------------- xgates via MFMA (transposed-D, bias folded) ----------------

__global__ __launch_bounds__(512, 2) void xgates_mfma(
    const __hip_bfloat16* __restrict__ Xd,     // [T][32]
    const __hip_bfloat16* __restrict__ W_ihp,  // [512][32] rows n''
    __hip_bfloat16* __restrict__ xg2)          // [T][512] cols n''
{
    const int tid = threadIdx.x;
    const int w8  = tid >> 6;
    const int l   = tid & 63;
    const int lr  = l & 15;
    const int lg  = l >> 4;
    const int t0  = blockIdx.x * 64;

    bf16x8 a[4];
#pragma unroll
    for (int mfx = 0; mfx < 4; ++mfx)
        a[mfx] = *reinterpret_cast<const bf16x8*>(
            W_ihp + (size_t)(w8 * 64 + mfx * 16 + lr) * 32 + lg * 8);

#pragma unroll
    for (int tt = 0; tt < 4; ++tt) {
        const int t = t0 + tt * 16 + lr;
        bf16x8 b = *reinterpret_cast<const bf16x8*>(Xd + (size_t)t * 32 + lg * 8);
#pragma unroll
        for (int mfx = 0; mfx < 4; ++mfx) {
            f32x4 acc = (f32x4){0.f, 0.f, 0.f, 0.f};
            acc = __builtin_amdgcn_mfma_f32_16x16x32_bf16(a[mfx], b, acc, 0, 0, 0);
            __hip_bfloat16 tmp[4];
#pragma unroll
            for (int r = 0; r < 4; ++r) tmp[r] = __float2bfloat16(acc[r]);
            *reinterpret_cast<uint2*>(xg2 + (size_t)t * G4 + w8 * 64 + mfx * 16 + lg * 4) =
                *reinterpret_cast<const uint2*>(tmp);
        }
    }
}

// ---------------- FNN via bf16 MFMA (unchanged, validated round 4) ----------------

__global__ __launch_bounds__(512, 2) void fnn_mfma(
    const __hip_bfloat16* __restrict__ Abf,
    const __hip_bfloat16* __restrict__ W1bf,
    const float* __restrict__ b1,
    const __hip_bfloat16* __restrict__ W2bf,
    const float* __restrict__ b2,
    float* __restrict__ out)
{
    __shared__ __attribute__((aligned(16))) __hip_bfloat16 c1[64][520];
    const int tid  = threadIdx.x;
    const int wid  = tid >> 6;
    const int lane = tid & 63;
    const int lr   = lane & 15;
    const int lg   = lane >> 4;
    const int wm   = wid >> 2;
    const int wn   = wid & 3;
    const int m0   = blockIdx.x * 64;

    f32x4 acc1[2][8];
#pragma unroll
    for (int i = 0; i < 2; ++i)
#pragma unroll
        for (int j = 0; j < 8; ++j)
            acc1[i][j] = (f32x4){0.f, 0.f, 0.f, 0.f};

#pragma unroll
    for (int ks = 0; ks < 3; ++ks) {
        const int k0 = ks * 32 + lg * 8;
        bf16x8 a[2], b[8];
#pragma unroll
        for (int mf = 0; mf < 2; ++mf) {
            const int row = m0 + wm * 32 + mf * 16 + lr;
            a[mf] = *reinterpret_cast<const bf16x8*>(Abf + (size_t)row * KP1 + k0);
        }
#pragma unroll
        for (int nf = 0; nf < 8; ++nf) {
            const int col = wn * 128 + nf * 16 + lr;
            b[nf] = *reinterpret_cast<const bf16x8*>(W1bf + (size_t)col * KP1 + k0);
        }
#pragma unroll
        for (int mf = 0; mf < 2; ++mf)
#pragma unroll
            for (int nf = 0; nf < 8; ++nf)
                acc1[mf][nf] = __builtin_amdgcn_mfma_f32_16x16x32_bf16(
                    a[mf], b[nf], acc1[mf][nf], 0, 0, 0);
    }

#pragma unroll
    for (int nf = 0; nf < 8; ++nf) {
        const int col = wn * 128 + nf * 16 + lr;
        const float bv = b1[col];
#pragma unroll
        for (int mf = 0; mf < 2; ++mf) {
            const int rowb = wm * 32 + mf * 16 + lg * 4;
#pragma unroll
            for (int r = 0; r < 4; ++r) {
                float v = fmaxf(acc1[mf][nf][r] + bv, 0.f);
                c1[rowb + r][col] = __float2bfloat16(v);
            }
        }
    }
    __syncthreads();

    f32x4 acc2[2][4];
#pragma unroll
    for (int i = 0; i < 2; ++i)
#pragma unroll
        for (int j = 0; j < 4; ++j)
            acc2[i][j] = (f32x4){0.f, 0.f, 0.f, 0.f};

#pragma unroll
    for (int ks = 0; ks < 16; ++ks) {
        const int k0 = ks * 32 + lg * 8;
        bf16x8 a[2], b[4];
#pragma unroll
        for (int mf = 0; mf < 2; ++mf) {
            const int row = wm * 32 + mf * 16 + lr;
            a[mf] = *reinterpret_cast<const bf16x8*>(&c1[row][k0]);
        }
#pragma unroll
        for (int nf = 0; nf < 4; ++nf) {
            const int col = wn * 64 + nf * 16 + lr;
            b[nf] = *reinterpret_cast<const bf16x8*>(W2bf + (size_t)col * H_FNN + k0);
        }
#pragma unroll
        for (int mf = 0; mf < 2; ++mf)
#pragma unroll
            for (int nf = 0; nf < 4; ++nf)
                acc2[mf][nf] = __builtin_amdgcn_mfma_f32_16x16x32_bf16(
                    a[mf], b[nf], acc2[mf][nf], 0, 0, 0);
    }

#pragma unroll
    for (int nf = 0; nf < 4; ++nf) {
        const int col = wn * 64 + nf * 16 + lr;
        const float bv = b2[col];
#pragma unroll
        for (int mf = 0; mf < 2; ++mf) {
#pragma unroll
            for (int r = 0; r < 4; ++r) {
                const int row = m0 + wm * 32 + mf * 16 + lg * 4 + r;
                float v = fmaxf(acc2[mf][nf][r] + bv, 0.f);
                out[(size_t)row * OUT_COLS + col] = v;
                out[((size_t)T_TOTAL + row) * OUT_COLS + col] = v;
            }
        }
    }
}

// ---------------- 2-blocks/CU MFMA LSTM (no xstage, no outbuf) ----------------
// R12 lesson: weight reloads were L2-resident and NOT the bottleneck (all 3 pin
// experiments neutral). The cost is the serial phase chain x 16-wave lockstep
// with 1 block/CU. This round: 512 blocks x 512 threads = 2 blocks/CU; when
// block A stalls in its chain, block B's waves fill the SIMDs.
//  - xg: direct per-lane uint2 global loads (4-step chunks, prefetched 1 chunk
//    ahead; per-wave rows coalesce to 128B). No xstage LDS.
//  - outputs: accumulated in 8 registers (full 48-step unroll -> static idx),
//    LDS bounce + coalesced stream at the end. No outbuf in the loop.
//  - LDS = hB 2.25KB + outb 17KB  (was 141KB -> enables 2 blocks/CU).
//  - gates^T = Whh3 @ H^T; all 64 lanes extract DISTINCT items from the
//    replicated D cols: lane(lr,lg): ch=lr&3, q=lr>>2, unit=w*16+q*4+lg,
//    gates = acc[q] (static 3-level cndmask select).
// DS ops/wave/step: 4 hB reads + 1 hB write = 5.

__global__ __attribute__((amdgpu_flat_work_group_size(512, 512),
                          amdgpu_waves_per_eu(4, 4)))
void lstm_mfma8(
    const __hip_bfloat16* __restrict__ xg2,    // [T][512] cols n''=4u+g
    const __hip_bfloat16* __restrict__ Whh3,   // [512][128] rows n'
    float* __restrict__ out)
{
    const int tid = threadIdx.x;
    const int l   = tid & 63;
    const int w   = tid >> 6;          // wave 0..7
    const int lr  = l & 15;
    const int lg  = l >> 4;
    const int ch  = lr & 3;            // this lane's chain
    const int q   = lr >> 2;           // which nf-group this lane updates
    const int u_up = w * 16 + q * 4 + lg;    // this lane's hidden unit

    __shared__ __attribute__((aligned(16))) __hip_bfloat16 hB[2][CPB][144];  // 2.25 KiB
    __shared__ __attribute__((aligned(8))) unsigned short outb[CPB][16][132]; // 16.5 KiB

    // A-fragments: Whh3 rows w*64 + nf*16 + lr (64 VGPRs; L2-resident if remat'd)
    bf16x8 afr[4][4];
#pragma unroll
    for (int nf = 0; nf < 4; ++nf)
#pragma unroll
        for (int ks = 0; ks < 4; ++ks)
            afr[nf][ks] = *reinterpret_cast<const bf16x8*>(
                Whh3 + (size_t)(w * 64 + nf * 16 + lr) * H_RNN + ks * 32 + lg * 8);

    const int tbase = blockIdx.x * (CPB * SEG) - BURN;
    const int tb_c  = tbase + ch * SEG;

    // per-lane xg address base (bytes): row t, col 8*u_up bytes
    auto xload = [&](int t) -> uint2 {
        int tc = t < 0 ? 0 : t;
        return *reinterpret_cast<const uint2*>(
            (const char*)xg2 + (size_t)tc * 1024 + 8 * u_up);
    };

    // prologue: zero hB, load chunk 0
    {
        uint32_t* hz = (uint32_t*)hB;            // 576 dwords
        if (tid < 576) hz[tid] = 0u;
    }
    uint2 cx0 = xload(tb_c + 0), cx1 = xload(tb_c + 1),
          cx2 = xload(tb_c + 2), cx3 = xload(tb_c + 3);
    uint2 nx0, nx1, nx2, nx3;

    unsigned int outreg[8];
    float c_st = 0.f;
    float h;
    __syncthreads();

#pragma unroll
    for (int i = 0; i < STEPS; ++i) {
        const int pb = i & 1;
        // prefetch next 4-step chunk of xg (1-step slack before this barrier's drain)
        if ((i & 3) == 0 && i + 4 < STEPS) {
            nx0 = xload(tb_c + i + 4); nx1 = xload(tb_c + i + 5);
            nx2 = xload(tb_c + i + 6); nx3 = xload(tb_c + i + 7);
        }

        // B-fragments: col = chain (cols 4..15 replicate chains 0..3)
        bf16x8 bfrg[4];
#pragma unroll
        for (int ks = 0; ks < 4; ++ks)
            bfrg[ks] = *reinterpret_cast<const bf16x8*>(&hB[pb][ch][ks * 32 + lg * 8]);

        f32x4 acc[4];
#pragma unroll
        for (int nf = 0; nf < 4; ++nf) acc[nf] = (f32x4){0.f, 0.f, 0.f, 0.f};
#pragma unroll
        for (int nf = 0; nf < 4; ++nf)
#pragma unroll
            for (int ks = 0; ks < 4; ++ks)
                acc[nf] = __builtin_amdgcn_mfma_f32_16x16x32_bf16(
                    afr[nf][ks], bfrg[ks], acc[nf], 0, 0, 0);

        // static select of this lane's nf-group (12 cndmask)
        f32x4 gs = q == 0 ? acc[0] : (q == 1 ? acc[1] : (q == 2 ? acc[2] : acc[3]));

        uint2 xr = (i & 3) == 0 ? cx0 : ((i & 3) == 1 ? cx1 : ((i & 3) == 2 ? cx2 : cx3));

        float g0 = gs[0] + __uint_as_float(xr.x << 16);
        float g1 = gs[1] + __uint_as_float(xr.x & 0xffff0000u);
        float g2 = gs[2] + __uint_as_float(xr.y << 16);
        float g3 = gs[3] + __uint_as_float(xr.y & 0xffff0000u);

        float I = fast_sigmoid(g0);
        float F = fast_sigmoid(g1);
        float G = fast_tanh  (g2);
        float O = fast_sigmoid(g3);
        float cn = F * c_st + I * G;
        const bool neg = (tb_c + i) < 0;
        c_st = neg ? 0.f : cn;
        h    = neg ? 0.f : O * fast_tanh(c_st);

        // h -> next B buffer at k = u_up (identity col perm), one b16/lane
        hB[pb ^ 1][ch][u_up] = __float2bfloat16(h);

        if (i >= BURN) {
            __hip_bfloat16 hb = __float2bfloat16(fmaxf(h, 0.f));
            unsigned int bits = *reinterpret_cast<unsigned short*>(&hb);
            const int st = i - BURN;                       // static under unroll
            if (st & 1) outreg[st >> 1] |= bits << 16;
            else        outreg[st >> 1]  = bits;
        }

        if ((i & 3) == 3 && i + 1 < STEPS) {
            cx0 = nx0; cx1 = nx1; cx2 = nx2; cx3 = nx3;
        }
        __syncthreads();
    }

    // ---- tail: regs -> LDS -> coalesced global stream ----
#pragma unroll
    for (int st = 0; st < 16; ++st)
        outb[ch][st][u_up] =
            (unsigned short)((outreg[st >> 1] >> ((st & 1) * 16)) & 0xffffu);
    __syncthreads();

    const unsigned int* ob32 = reinterpret_cast<const unsigned int*>(&outb[0][0][0]);
#pragma unroll
    for (int k = 0; k < 8; ++k) {
        int idx  = k * 512 + tid;               // 0..4095 dwords
        int row  = idx >> 6;                    // ch*16 + st
        int cold = idx & 63;                    // unit pair
        unsigned int v2 = ob32[row * 66 + cold];
        float v0 = __uint_as_float(v2 << 16);
        float v1 = __uint_as_float(v2 & 0xffff0000u);
        size_t t = (size_t)blockIdx.x * 64 + row;
        float2* po = reinterpret_cast<float2*>(out + t * OUT_COLS + 256 + 2 * cold);
        *po = make_float2(v0, v1);
        po = reinterpret_cast<float2*>(out + ((size_t)T_TOTAL + t) * OUT_COLS + 256 + 2 * cold);
        *po = make_float2(v0, v1);
    }
}

// ---------------- host ----------------

extern "C" void kernel_launch(void* const* d_in, const int* in_sizes, int n_in,
                              void* d_out, int out_size, void* d_ws, size_t ws_size,
                              hipStream_t stream) {
    const float* features = (const float*)d_in[0];
    const float* W1   = (const float*)d_in[1];
    const float* b1   = (const float*)d_in[2];
    const float* W2   = (const float*)d_in[3];
    const float* b2   = (const float*)d_in[4];
    const float* W_ih = (const float*)d_in[5];
    const float* b_ih = (const float*)d_in[6];
    const float* W_hh = (const float*)d_in[7];
    const float* b_hh = (const float*)d_in[8];
    float* out = (float*)d_out;

    char* ws = (char*)d_ws;
    __hip_bfloat16* xg2   = (__hip_bfloat16*)ws;                     // 32 MiB
    size_t off = (size_t)T_TOTAL * G4 * 2;
    __hip_bfloat16* Abf   = (__hip_bfloat16*)(ws + off); off += (size_t)N_A * 2;
    __hip_bfloat16* W1b   = (__hip_bfloat16*)(ws + off); off += (size_t)N_W1 * 2;
    __hip_bfloat16* W2b   = (__hip_bfloat16*)(ws + off); off += (size_t)N_W2 * 2;
    __hip_bfloat16* Whh3  = (__hip_bfloat16*)(ws + off); off += (size_t)N_WHH * 2;
    __hip_bfloat16* W_ihp = (__hip_bfloat16*)(ws + off); off += (size_t)N_WIH * 2;
    __hip_bfloat16* Xd    = (__hip_bfloat16*)(ws + off);

    hipLaunchKernelGGL(prep_kernel, dim3((N_TOT + 255) / 256), dim3(256), 0, stream,
                       features, W1, W2, W_ih, b_ih, b_hh, W_hh,
                       Abf, W1b, W2b, Whh3, W_ihp, Xd);
    hipLaunchKernelGGL(xgates_mfma, dim3(T_TOTAL / 64), dim3(512), 0, stream,
                       Xd, W_ihp, xg2);
    hipLaunchKernelGGL(fnn_mfma,    dim3(T_TOTAL / 64), dim3(512), 0, stream,
                       Abf, W1b, b1, W2b, b2, out);
    hipLaunchKernelGGL(lstm_mfma8,  dim3(NBLK), dim3(512), 0, stream, xg2, Whh3, out);
}